// Round 1
// baseline (94.052 us; speedup 1.0000x reference)
//
#include <hip/hip_runtime.h>

#define N_GENES 768
#define H 128
#define TILE 48      // 48x48 pair tile per block -> 16x16 = 256 blocks exactly
#define LDP 132      // padded row stride (floats): +4 keeps 16B alignment, breaks bank aliasing

// ---------------------------------------------------------------------------
// Kernel A: per-gene projections (tiny GEMMs), f64 accumulate for accuracy.
//   AiB[i][m] = sum_k X[i][k]*W1[m][k]      + b1[m]
//   Bjp[i][m] = sum_k X[i][k]*W1[m][H+k]
//   Y  [i][m] = sum_k X[i][k]*Wb[k][m]
// grid 192 blocks x 128 threads, 4 genes per block, thread = output column m.
// ---------------------------------------------------------------------------
__global__ __launch_bounds__(128) void grn_pre(
    const float* __restrict__ X, const float* __restrict__ W1,
    const float* __restrict__ b1, const float* __restrict__ Wb,
    float* __restrict__ AiB, float* __restrict__ Bjp, float* __restrict__ Y)
{
    const int m  = threadIdx.x;       // 0..127
    const int g0 = blockIdx.x * 4;    // first gene row of this block

    __shared__ float Xs[4][H];
    #pragma unroll
    for (int r = 0; r < 4; ++r) Xs[r][m] = X[(g0 + r) * H + m];
    __syncthreads();

    double aib[4] = {0, 0, 0, 0}, bj[4] = {0, 0, 0, 0}, y[4] = {0, 0, 0, 0};
    const float4* W1a = (const float4*)(W1 + m * (2 * H));
    const float4* W1b = (const float4*)(W1 + m * (2 * H) + H);

    #pragma unroll 4
    for (int kq = 0; kq < H / 4; ++kq) {
        float4 wa = W1a[kq];
        float4 wb = W1b[kq];
        float wc[4];
        #pragma unroll
        for (int e = 0; e < 4; ++e) wc[e] = Wb[(kq * 4 + e) * H + m];  // coalesced across m
        const float* wae = &wa.x;
        const float* wbe = &wb.x;
        #pragma unroll
        for (int r = 0; r < 4; ++r) {
            float4 xr = *(const float4*)&Xs[r][kq * 4];
            const float* xe = &xr.x;
            #pragma unroll
            for (int e = 0; e < 4; ++e) {
                aib[r] += (double)xe[e] * (double)wae[e];
                bj[r]  += (double)xe[e] * (double)wbe[e];
                y[r]   += (double)xe[e] * (double)wc[e];
            }
        }
    }

    const double b1m = (double)b1[m];
    #pragma unroll
    for (int r = 0; r < 4; ++r) {
        AiB[(g0 + r) * H + m] = (float)(aib[r] + b1m);
        Bjp[(g0 + r) * H + m] = (float)bj[r];
        Y  [(g0 + r) * H + m] = (float)y[r];
    }
}

// ---------------------------------------------------------------------------
// Tile loader: 48 rows x 128 floats (1536 float4) by 256 threads, coalesced,
// stored with padded stride LDP (row*528B stays 16B-aligned).
// ---------------------------------------------------------------------------
__device__ __forceinline__ void load_tile(float* __restrict__ dst,
                                          const float* __restrict__ src, int tx)
{
    #pragma unroll
    for (int t = 0; t < 6; ++t) {
        int idx = tx + t * 256;       // 0..1535
        int row = idx >> 5;           // 32 float4 per row
        int c4  = idx & 31;
        *(float4*)&dst[row * LDP + c4 * 4] = *(const float4*)&src[row * H + c4 * 4];
    }
}

// ---------------------------------------------------------------------------
// Kernel B: fused main. Grid 16x16 = 256 blocks (one per CU, no tail),
// 256 threads, 3x3 pairs per thread (rows i = it+{0,16,32}, cols j likewise
// for coalesced stores). Two phases over shared LDS buffers:
//   phase 1: aff[r][c] = Y[i]·X[j]
//   phase 2: u = l0-l2, v = l0-l1 via h=relu(AiB[i]+Bjp[j]) against W2 diffs
// ---------------------------------------------------------------------------
__global__ __launch_bounds__(256) void grn_main(
    const float* __restrict__ AiB, const float* __restrict__ Bjp,
    const float* __restrict__ Y,   const float* __restrict__ X,
    const float* __restrict__ W2,  const float* __restrict__ b2,
    const float* __restrict__ bb,  float* __restrict__ out)
{
    const int gj = blockIdx.x & 15;
    const int gi = blockIdx.x >> 4;
    const int tx = threadIdx.x;
    const int it = tx >> 4;   // 0..15 -> i rows it+{0,16,32}
    const int jt = tx & 15;   // 0..15 -> j cols jt+{0,16,32}

    __shared__ float sL[TILE * LDP];   // left  tile: Y, then AiB
    __shared__ float sR[TILE * LDP];   // right tile: X, then Bjp
    __shared__ float sW0[H];           // W2[0]-W2[2]  (drives u = l0-l2)
    __shared__ float sW1[H];           // W2[0]-W2[1]  (drives v = l0-l1)

    // ---- phase 1: affinity ----
    load_tile(sL, Y + gi * TILE * H, tx);
    load_tile(sR, X + gj * TILE * H, tx);
    if (tx < H) {
        sW0[tx] = W2[tx] - W2[2 * H + tx];
        sW1[tx] = W2[tx] - W2[H + tx];
    }
    __syncthreads();

    float aff[3][3] = {};
    #pragma unroll 4
    for (int mq = 0; mq < H / 4; ++mq) {
        float4 yv[3], xv[3];
        #pragma unroll
        for (int r = 0; r < 3; ++r) yv[r] = *(const float4*)&sL[(it + 16 * r) * LDP + mq * 4];
        #pragma unroll
        for (int c = 0; c < 3; ++c) xv[c] = *(const float4*)&sR[(jt + 16 * c) * LDP + mq * 4];
        #pragma unroll
        for (int r = 0; r < 3; ++r) {
            const float* ye = &yv[r].x;
            #pragma unroll
            for (int c = 0; c < 3; ++c) {
                const float* xe = &xv[c].x;
                #pragma unroll
                for (int e = 0; e < 4; ++e)
                    aff[r][c] = fmaf(ye[e], xe[e], aff[r][c]);
            }
        }
    }

    __syncthreads();   // everyone done reading phase-1 tiles

    // ---- phase 2: logit differences ----
    load_tile(sL, AiB + gi * TILE * H, tx);
    load_tile(sR, Bjp + gj * TILE * H, tx);
    __syncthreads();

    const float u0 = b2[0] - b2[2];
    const float v0 = b2[0] - b2[1];
    float u[3][3], v[3][3];
    #pragma unroll
    for (int r = 0; r < 3; ++r)
        #pragma unroll
        for (int c = 0; c < 3; ++c) { u[r][c] = u0; v[r][c] = v0; }

    #pragma unroll 4
    for (int mq = 0; mq < H / 4; ++mq) {
        float4 w0 = *(const float4*)&sW0[mq * 4];
        float4 w1 = *(const float4*)&sW1[mq * 4];
        const float* w0e = &w0.x;
        const float* w1e = &w1.x;
        float4 av[3], bv[3];
        #pragma unroll
        for (int r = 0; r < 3; ++r) av[r] = *(const float4*)&sL[(it + 16 * r) * LDP + mq * 4];
        #pragma unroll
        for (int c = 0; c < 3; ++c) bv[c] = *(const float4*)&sR[(jt + 16 * c) * LDP + mq * 4];
        #pragma unroll
        for (int r = 0; r < 3; ++r) {
            const float* ae = &av[r].x;
            #pragma unroll
            for (int c = 0; c < 3; ++c) {
                const float* be = &bv[c].x;
                #pragma unroll
                for (int e = 0; e < 4; ++e) {
                    float h = fmaxf(ae[e] + be[e], 0.0f);
                    u[r][c] = fmaf(h, w0e[e], u[r][c]);
                    v[r][c] = fmaf(h, w1e[e], v[r][c]);
                }
            }
        }
    }

    // ---- epilogue: sign select, bilinear bias, zero diagonal ----
    const float bbv = bb[0];
    #pragma unroll
    for (int r = 0; r < 3; ++r) {
        const int i = gi * TILE + it + 16 * r;
        #pragma unroll
        for (int c = 0; c < 3; ++c) {
            const int j = gj * TILE + jt + 16 * c;
            float A = aff[r][c] + bbv;
            float uu = u[r][c], vv = v[r][c];
            // argmax(l0,l1,l2) first-max semantics:
            // cls0: l0>=l1 && l0>=l2  <=>  vv>=0 && uu>=0   -> +A
            // cls2: l2>l0 && l2>l1    <=>  uu<0  && uu<vv   -> -A
            float s = (uu >= 0.0f && vv >= 0.0f) ? A
                    : ((uu < 0.0f && uu < vv) ? -A : 0.0f);
            if (i == j) s = 0.0f;
            out[i * N_GENES + j] = s;
        }
    }
}

extern "C" void kernel_launch(void* const* d_in, const int* in_sizes, int n_in,
                              void* d_out, int out_size, void* d_ws, size_t ws_size,
                              hipStream_t stream)
{
    const float* X  = (const float*)d_in[0];  // [768,128]
    const float* W1 = (const float*)d_in[1];  // [128,256]
    const float* b1 = (const float*)d_in[2];  // [128]
    const float* W2 = (const float*)d_in[3];  // [3,128]
    const float* b2 = (const float*)d_in[4];  // [3]
    const float* Wb = (const float*)d_in[5];  // [1,128,128]
    const float* bb = (const float*)d_in[6];  // [1]
    float* out = (float*)d_out;

    float* ws  = (float*)d_ws;
    float* AiB = ws;                      // 768*128 floats
    float* Bjp = ws + N_GENES * H;        // 768*128
    float* Yw  = ws + 2 * N_GENES * H;    // 768*128

    grn_pre <<<N_GENES / 4, 128, 0, stream>>>(X, W1, b1, Wb, AiB, Bjp, Yw);
    grn_main<<<256,         256, 0, stream>>>(AiB, Bjp, Yw, X, W2, b2, bb, out);
}

// Round 2
// 88.325 us; speedup vs baseline: 1.0648x; 1.0648x over previous
//
#include <hip/hip_runtime.h>

#define N_GENES 768
#define H 128
#define TILE 48      // 48x48 pair tile per block -> 16x16 = 256 blocks exactly
#define LDP 132      // f32 LDS row stride: +4 keeps 16B alignment, breaks bank aliasing
#define LDPH 136     // f16 LDS row stride in halves: 272B rows, 16B-aligned, bank shift 4

typedef float    f2 __attribute__((ext_vector_type(2)));
typedef _Float16 h2 __attribute__((ext_vector_type(2)));
typedef _Float16 h8 __attribute__((ext_vector_type(8)));

// ---------------------------------------------------------------------------
// Kernel A: per-gene projections, f64 accumulate (bit-identical math to R1;
// only the grid grouping changed 4->3 rows so grid=256 covers all CUs).
//   AiB[i][m] = sum_k X[i][k]*W1[m][k] + b1[m]
//   Bjp[i][m] = sum_k X[i][k]*W1[m][H+k]
//   Yh [i][m] = f16( sum_k X[i][k]*Wb[k][m] )   (phase-1 affinity operand)
//   Xh [i][m] = f16( X[i][m] )
// ---------------------------------------------------------------------------
__global__ __launch_bounds__(128) void grn_pre(
    const float* __restrict__ X, const float* __restrict__ W1,
    const float* __restrict__ b1, const float* __restrict__ Wb,
    float* __restrict__ AiB, float* __restrict__ Bjp,
    _Float16* __restrict__ Yh, _Float16* __restrict__ Xh)
{
    const int m  = threadIdx.x;       // 0..127
    const int g0 = blockIdx.x * 3;    // first gene row of this block (256 blocks)

    __shared__ float Xs[3][H];
    #pragma unroll
    for (int r = 0; r < 3; ++r) Xs[r][m] = X[(g0 + r) * H + m];
    __syncthreads();

    double aib[3] = {0, 0, 0}, bj[3] = {0, 0, 0}, y[3] = {0, 0, 0};
    const float4* W1a = (const float4*)(W1 + m * (2 * H));
    const float4* W1b = (const float4*)(W1 + m * (2 * H) + H);

    #pragma unroll 4
    for (int kq = 0; kq < H / 4; ++kq) {
        float4 wa = W1a[kq];
        float4 wb = W1b[kq];
        float wc[4];
        #pragma unroll
        for (int e = 0; e < 4; ++e) wc[e] = Wb[(kq * 4 + e) * H + m];  // coalesced across m
        const float* wae = &wa.x;
        const float* wbe = &wb.x;
        #pragma unroll
        for (int r = 0; r < 3; ++r) {
            float4 xr = *(const float4*)&Xs[r][kq * 4];
            const float* xe = &xr.x;
            #pragma unroll
            for (int e = 0; e < 4; ++e) {
                aib[r] += (double)xe[e] * (double)wae[e];
                bj[r]  += (double)xe[e] * (double)wbe[e];
                y[r]   += (double)xe[e] * (double)wc[e];
            }
        }
    }

    const double b1m = (double)b1[m];
    #pragma unroll
    for (int r = 0; r < 3; ++r) {
        AiB[(g0 + r) * H + m] = (float)(aib[r] + b1m);
        Bjp[(g0 + r) * H + m] = (float)bj[r];
        Yh [(g0 + r) * H + m] = (_Float16)(float)y[r];
        Xh [(g0 + r) * H + m] = (_Float16)Xs[r][m];
    }
}

// f32 tile loader: 48 rows x 128 floats (1536 float4) by 256 threads, coalesced.
__device__ __forceinline__ void load_tile_f32(float* __restrict__ dst,
                                              const float* __restrict__ src, int tx)
{
    #pragma unroll
    for (int t = 0; t < 6; ++t) {
        int idx = tx + t * 256;       // 0..1535
        int row = idx >> 5;           // 32 float4 per row
        int c4  = idx & 31;
        *(float4*)&dst[row * LDP + c4 * 4] = *(const float4*)&src[row * H + c4 * 4];
    }
}

// f16 tile loader: 48 rows x 128 halves (768 x 16B) by 256 threads.
__device__ __forceinline__ void load_tile_f16(_Float16* __restrict__ dst,
                                              const _Float16* __restrict__ src, int tx)
{
    #pragma unroll
    for (int t = 0; t < 3; ++t) {
        int idx = tx + t * 256;       // 0..767
        int row = idx >> 4;           // 16 h8 per row
        int c8  = idx & 15;
        *(h8*)&dst[row * LDPH + c8 * 8] = *(const h8*)&src[row * H + c8 * 8];
    }
}

__device__ __forceinline__ h2 hpair(h8 v, int p) { h2 r; r.x = v[2*p]; r.y = v[2*p+1]; return r; }

// ---------------------------------------------------------------------------
// Kernel B: fused main. 256 blocks (one/CU), 256 threads, 3x3 pairs/thread.
// Phase 1: affinity via f16 v_dot2 (half the LDS traffic of f32).
// Phase 2: u=l0-l2, v=l0-l1 with h=relu(a+b) in packed f32 (bit-identical h),
//          u/v FMA chains kept scalar in R1's exact order (argmax-tie safety).
// ---------------------------------------------------------------------------
__global__ __launch_bounds__(256) void grn_main(
    const float* __restrict__ AiB, const float* __restrict__ Bjp,
    const _Float16* __restrict__ Yh, const _Float16* __restrict__ Xh,
    const float* __restrict__ W2,  const float* __restrict__ b2,
    const float* __restrict__ bb,  float* __restrict__ out)
{
    const int gj = blockIdx.x & 15;
    const int gi = blockIdx.x >> 4;
    const int tx = threadIdx.x;
    const int it = tx >> 4;   // 0..15 -> i rows it+{0,16,32}
    const int jt = tx & 15;   // 0..15 -> j cols jt+{0,16,32}

    __shared__ float sL[TILE * LDP];   // phase1: f16 Y tile (aliased); phase2: AiB tile
    __shared__ float sR[TILE * LDP];   // phase1: f16 X tile (aliased); phase2: Bjp tile
    __shared__ float sW[2 * H];        // [0..127]=W2[0]-W2[2] (u), [128..255]=W2[0]-W2[1] (v)

    _Float16* sLh = (_Float16*)sL;
    _Float16* sRh = (_Float16*)sR;

    // ---- phase 1: affinity (f16 storage, f32 accumulate via v_dot2) ----
    load_tile_f16(sLh, Yh + gi * TILE * H, tx);
    load_tile_f16(sRh, Xh + gj * TILE * H, tx);
    if (tx < H) {
        sW[tx]     = W2[tx] - W2[2 * H + tx];
        sW[H + tx] = W2[tx] - W2[H + tx];
    }
    __syncthreads();

    float aff[3][3] = {};
    #pragma unroll 2
    for (int q = 0; q < H / 8; ++q) {
        h8 yv[3], xv[3];
        #pragma unroll
        for (int r = 0; r < 3; ++r) yv[r] = *(const h8*)&sLh[(it + 16 * r) * LDPH + q * 8];
        #pragma unroll
        for (int c = 0; c < 3; ++c) xv[c] = *(const h8*)&sRh[(jt + 16 * c) * LDPH + q * 8];
        #pragma unroll
        for (int r = 0; r < 3; ++r)
            #pragma unroll
            for (int c = 0; c < 3; ++c)
                #pragma unroll
                for (int p = 0; p < 4; ++p) {
#if __has_builtin(__builtin_amdgcn_fdot2)
                    aff[r][c] = __builtin_amdgcn_fdot2(hpair(yv[r], p), hpair(xv[c], p),
                                                       aff[r][c], false);
#else
                    h2 a = hpair(yv[r], p), b = hpair(xv[c], p);
                    aff[r][c] = fmaf((float)a.x, (float)b.x, aff[r][c]);
                    aff[r][c] = fmaf((float)a.y, (float)b.y, aff[r][c]);
#endif
                }
    }

    __syncthreads();   // everyone done reading phase-1 tiles

    // ---- phase 2: logit differences ----
    load_tile_f32(sL, AiB + gi * TILE * H, tx);
    load_tile_f32(sR, Bjp + gj * TILE * H, tx);
    __syncthreads();

    const float u0 = b2[0] - b2[2];
    const float v0 = b2[0] - b2[1];
    float u[3][3], v[3][3];
    #pragma unroll
    for (int r = 0; r < 3; ++r)
        #pragma unroll
        for (int c = 0; c < 3; ++c) { u[r][c] = u0; v[r][c] = v0; }

    const f2 zero2 = {0.0f, 0.0f};
    #pragma unroll 4
    for (int mq = 0; mq < H / 4; ++mq) {
        float4 w0 = *(const float4*)&sW[mq * 4];
        float4 w1 = *(const float4*)&sW[H + mq * 4];
        float4 av[3], bv[3];
        #pragma unroll
        for (int r = 0; r < 3; ++r) av[r] = *(const float4*)&sL[(it + 16 * r) * LDP + mq * 4];
        #pragma unroll
        for (int c = 0; c < 3; ++c) bv[c] = *(const float4*)&sR[(jt + 16 * c) * LDP + mq * 4];
        #pragma unroll
        for (int r = 0; r < 3; ++r) {
            f2 a01 = {av[r].x, av[r].y};
            f2 a23 = {av[r].z, av[r].w};
            #pragma unroll
            for (int c = 0; c < 3; ++c) {
                f2 b01 = {bv[c].x, bv[c].y};
                f2 b23 = {bv[c].z, bv[c].w};
                // packed relu(a+b): elementwise -> bit-identical to scalar R1
                f2 h01 = __builtin_elementwise_max(a01 + b01, zero2);
                f2 h23 = __builtin_elementwise_max(a23 + b23, zero2);
                // scalar FMA chains in R1's exact e=0..3 order (tie safety)
                float uu = u[r][c], vv = v[r][c];
                uu = fmaf(h01.x, w0.x, uu); vv = fmaf(h01.x, w1.x, vv);
                uu = fmaf(h01.y, w0.y, uu); vv = fmaf(h01.y, w1.y, vv);
                uu = fmaf(h23.x, w0.z, uu); vv = fmaf(h23.x, w1.z, vv);
                uu = fmaf(h23.y, w0.w, uu); vv = fmaf(h23.y, w1.w, vv);
                u[r][c] = uu; v[r][c] = vv;
            }
        }
    }

    // ---- epilogue: sign select, bilinear bias, zero diagonal ----
    const float bbv = bb[0];
    #pragma unroll
    for (int r = 0; r < 3; ++r) {
        const int i = gi * TILE + it + 16 * r;
        #pragma unroll
        for (int c = 0; c < 3; ++c) {
            const int j = gj * TILE + jt + 16 * c;
            float A = aff[r][c] + bbv;
            float uu = u[r][c], vv = v[r][c];
            // cls0: vv>=0 && uu>=0 -> +A ; cls2: uu<0 && uu<vv -> -A ; else 0
            float s = (uu >= 0.0f && vv >= 0.0f) ? A
                    : ((uu < 0.0f && uu < vv) ? -A : 0.0f);
            if (i == j) s = 0.0f;
            out[i * N_GENES + j] = s;
        }
    }
}

extern "C" void kernel_launch(void* const* d_in, const int* in_sizes, int n_in,
                              void* d_out, int out_size, void* d_ws, size_t ws_size,
                              hipStream_t stream)
{
    const float* X  = (const float*)d_in[0];  // [768,128]
    const float* W1 = (const float*)d_in[1];  // [128,256]
    const float* b1 = (const float*)d_in[2];  // [128]
    const float* W2 = (const float*)d_in[3];  // [3,128]
    const float* b2 = (const float*)d_in[4];  // [3]
    const float* Wb = (const float*)d_in[5];  // [1,128,128]
    const float* bb = (const float*)d_in[6];  // [1]
    float* out = (float*)d_out;

    float* ws  = (float*)d_ws;
    float*     AiB = ws;                          // 768*128 f32
    float*     Bjp = ws + N_GENES * H;            // 768*128 f32
    _Float16*  Yh  = (_Float16*)(ws + 2 * N_GENES * H);           // 768*128 f16
    _Float16*  Xh  = (_Float16*)(ws + 2 * N_GENES * H) + N_GENES * H;

    grn_pre <<<N_GENES / 3, 128, 0, stream>>>(X, W1, b1, Wb, AiB, Bjp, Yh, Xh);
    grn_main<<<256,         256, 0, stream>>>(AiB, Bjp, Yh, Xh, W2, b2, bb, out);
}